// Round 4
// baseline (676.977 us; speedup 1.0000x reference)
//
#include <hip/hip_runtime.h>
#include <cstdint>

#define BATCH 8
#define NPTS  4096
#define MPTS  1024
#define DIM   64

typedef float v2f __attribute__((ext_vector_type(2)));
typedef unsigned long long u64;
typedef unsigned int u32;

// Pack (f32 distance bits, aux) into a double whose VALUE ordering equals the
// u64 bit-pattern ordering: hi word = f32 bits of a non-negative float
// (<= FLT_MAX bits 0x7F7FFFFF -> f64 exponent <= 2039, sign 0 -> positive
// finite double, never NaN/Inf). So v_max_f64 gives exact u64 max, and f64
// equality == bitwise equality (no -0 possible: lo=~idx never 0 with sign).
__device__ __forceinline__ double mk_key(float m, u32 aux) {
  const u64 k = ((u64)__float_as_uint(m) << 32) | (u64)aux;
  return __longlong_as_double((long long)k);
}
__device__ __forceinline__ u32 key_lo(double d) {
  return (u32)(u64)__double_as_longlong(d);
}

// One DPP step of a 64-lane f64-key max reduction. bound_ctrl=true -> invalid
// source lanes read 0.0, the identity for max of positive keys.
#define WAVE_MAX_F64_STEP(x, ctrl)                                                    \
  {                                                                                   \
    const u64 xu_ = (u64)__double_as_longlong(x);                                     \
    const int lo_ = __builtin_amdgcn_update_dpp(0, (int)(u32)xu_, (ctrl), 0xf, 0xf, true);  \
    const int hi_ = __builtin_amdgcn_update_dpp(0, (int)(u32)(xu_ >> 32), (ctrl), 0xf, 0xf, true); \
    const double y_ = __longlong_as_double((long long)(((u64)(u32)hi_ << 32) | (u64)(u32)lo_)); \
    (x) = fmax((x), y_);                                                              \
  }

// -------------------- Kernel 1: farthest point sampling --------------------
// One block per cloud, 256 threads (4 waves, 1/SIMD — R2 showed more waves
// duplicate reduce issue; R3 showed the f64-key reduce is the cheap form).
// R4 change: remove the post-barrier sp[widx] LDS hop from the critical path.
//  - After the local tree, each lane gathers sp[own local-best idx]
//    (ds_read_b128, per-lane addr) SPECULATIVELY — overlapped with the 6-step
//    DPP chain, so its ~130cy latency is hidden.
//  - Lane63's wave-max key is broadcast via 2x readlane (SGPR). Keys are
//    unique (contain idx), so exactly one lane per wave matches: that lane
//    publishes {key, coords} to its wave slot (sK/sA, double-buffered).
//  - Post-barrier: read 4 keys + 4 coord-vecs in parallel (ONE LDS hop),
//    3 fmax_f64 + cndmask-select coords. No dependent second read.
// Steady-state loop still has zero VMEM (R1); winner history in registers,
// gidx written in the epilogue.
__global__ __launch_bounds__(256) void fps_kernel(const float* __restrict__ pos,
                                                  int* __restrict__ gidx) {
#pragma clang fp contract(off)
  const int b = blockIdx.x;
  const int t = threadIdx.x;
  const float* p = pos + (size_t)b * NPTS * 3;

  __shared__ float4 sp[NPTS];
  __shared__ double sK[2][4];   // per-wave winner key
  __shared__ float4 sA[2][4];   // per-wave winner coords

  v2f px[8], py[8], pz[8], mind[8];
#pragma unroll
  for (int k = 0; k < 16; ++k) {
    const int i = t + k * 256;
    const float a = p[3 * i + 0];
    const float c = p[3 * i + 1];
    const float d = p[3 * i + 2];
    sp[i] = make_float4(a, c, d, 0.0f);
    px[k >> 1][k & 1] = a;
    py[k >> 1][k & 1] = c;
    pz[k >> 1][k & 1] = d;
    mind[k >> 1][k & 1] = 3.402823466e+38f;  // finfo(float32).max
  }
  __syncthreads();

  float4 w = sp[0];
  float lx = w.x, ly = w.y, lz = w.z;
  const int wid = t >> 6;  // wave id

  // Register history of winner indices: thread t owns iterations
  // t, t+256, t+512, t+768. h0 stays 0 for t==0 (deterministic start).
  int h0 = 0, h1 = 0, h2 = 0, h3 = 0;
  const int it1 = t + 256, it2 = t + 512, it3 = t + 768;

  for (int it = 1; it < MPTS; ++it) {
    const v2f vlx = {lx, lx}, vly = {ly, ly}, vlz = {lz, lz};
    double pg[8];
#pragma unroll
    for (int g = 0; g < 8; ++g) {
      // strict fp32, no contraction: ((dx*dx + dy*dy) + dz*dz), per element
      const v2f dx = px[g] - vlx;
      const v2f dy = py[g] - vly;
      const v2f dz = pz[g] - vlz;
      const v2f d = (dx * dx + dy * dy) + dz * dz;
      const v2f m = __builtin_elementwise_min(mind[g], d);
      mind[g] = m;
      const double p0 = mk_key(m[0], ~(u32)(t + (2 * g) * 256));      // hoisted consts
      const double p1 = mk_key(m[1], ~(u32)(t + (2 * g + 1) * 256));  // tie -> larger ~idx
      pg[g] = fmax(p0, p1);
    }
    // thread-local tree (all single v_max_f64)
    const double b0 = fmax(pg[0], pg[1]);
    const double b1 = fmax(pg[2], pg[3]);
    const double b2 = fmax(pg[4], pg[5]);
    const double b3 = fmax(pg[6], pg[7]);
    const double best = fmax(fmax(b0, b1), fmax(b2, b3));

    // Speculative gather of my local-best coords — overlaps the DPP chain.
    const u32 ow = ~key_lo(best);
    const float4 wc = sp[ow];

    // 64-lane wave max via DPP: rows (16) then cross-row bcasts; lane63 final.
    double wm = best;
    WAVE_MAX_F64_STEP(wm, 0x111);  // row_shr:1
    WAVE_MAX_F64_STEP(wm, 0x112);  // row_shr:2
    WAVE_MAX_F64_STEP(wm, 0x114);  // row_shr:4
    WAVE_MAX_F64_STEP(wm, 0x118);  // row_shr:8
    WAVE_MAX_F64_STEP(wm, 0x142);  // row_bcast:15
    WAVE_MAX_F64_STEP(wm, 0x143);  // row_bcast:31

    // Broadcast lane63's wave max to all lanes via SGPRs.
    const u64 wmb = (u64)__double_as_longlong(wm);
    const u32 mhi = (u32)__builtin_amdgcn_readlane((int)(u32)(wmb >> 32), 63);
    const u32 mlo = (u32)__builtin_amdgcn_readlane((int)(u32)wmb, 63);
    const u64 wmax = ((u64)mhi << 32) | (u64)mlo;

    const int buf = it & 1;  // double-buffered slots: 1 barrier/iter
    // Unique winner lane (keys contain idx -> distinct) publishes key+coords.
    if ((u64)__double_as_longlong(best) == wmax) {
      sK[buf][wid] = best;
      sA[buf][wid] = wc;
    }
    __syncthreads();

    // One parallel LDS hop: 4 keys + 4 coord-vecs; select max and its coords.
    const double k0 = sK[buf][0], k1 = sK[buf][1], k2 = sK[buf][2], k3 = sK[buf][3];
    const float4 a0 = sA[buf][0], a1 = sA[buf][1], a2 = sA[buf][2], a3 = sA[buf][3];
    const double c01 = fmax(k0, k1), c23 = fmax(k2, k3);
    const double c = fmax(c01, c23);
    const bool s1 = (c01 == k1);  // exact: keys unique, positive finite
    const bool s3 = (c23 == k3);
    const bool sh = (c == c23);
    const float ux = s1 ? a1.x : a0.x, uy = s1 ? a1.y : a0.y, uz = s1 ? a1.z : a0.z;
    const float vx2 = s3 ? a3.x : a2.x, vy2 = s3 ? a3.y : a2.y, vz2 = s3 ? a3.z : a2.z;
    lx = sh ? vx2 : ux; ly = sh ? vy2 : uy; lz = sh ? vz2 : uz;
    const u32 widx = ~key_lo(c);  // low word = ~idx

    // off-critical-path register history update (4x cmp+cndmask, no VMEM)
    h0 = (it == t)   ? (int)widx : h0;
    h1 = (it == it1) ? (int)widx : h1;
    h2 = (it == it2) ? (int)widx : h2;
    h3 = (it == it3) ? (int)widx : h3;
  }

  // Epilogue: 4 coalesced stores per thread write all M winner indices.
  const int base = b * MPTS;
  const int goff = b * NPTS;
  gidx[base + t]       = goff + h0;
  gidx[base + 256 + t] = goff + h1;
  gidx[base + 512 + t] = goff + h2;
  gidx[base + 768 + t] = goff + h3;
}

// ---------------- Kernel 2: fused k=1 NN + output assembly -----------------
// B*32 blocks x 256 threads; phase 1 = nn (128 hr points/block, 2 threads per
// point splitting M=1024 lr points in half, packed fp32, u64-key argmin with
// tie -> smallest j). nng stays in LDS (no global round-trip, one launch
// saved). Phase 2 = assembly: same (row, half) mapping; half0 writes
// [x(64)|pos(3)] + zeros, half1 writes [x[g](64)|pos[g](3)] + batch.
__global__ __launch_bounds__(256) void nn_assemble_kernel(
    const float* __restrict__ x, const float* __restrict__ pos,
    const int* __restrict__ batch, const int* __restrict__ gidx,
    float* __restrict__ out) {
#pragma clang fp contract(off)
  const int b = blockIdx.x >> 5;
  const int chunk = blockIdx.x & 31;
  const int t = threadIdx.x;

  __shared__ float lrx[MPTS], lry[MPTS], lrz[MPTS];
  __shared__ int snn[128];

  for (int j = t; j < MPTS; j += 256) {
    const int g = gidx[b * MPTS + j];
    lrx[j] = pos[3 * g + 0];
    lry[j] = pos[3 * g + 1];
    lrz[j] = pos[3 * g + 2];
  }
  __syncthreads();

  const int r = t >> 1;      // local row 0..127
  const int half = t & 1;
  const int i = b * NPTS + chunk * 128 + r;  // global hr point index
  const float X = pos[3 * i + 0];
  const float Y = pos[3 * i + 1];
  const float Z = pos[3 * i + 2];
  const v2f vX = {X, X}, vY = {Y, Y}, vZ = {Z, Z};

  double best = __longlong_as_double(0x7FEFFFFFFFFFFFFFll);  // +DBL_MAX > all keys
  const int j0 = half * 512;
#pragma unroll 4
  for (int s = 0; s < 256; ++s) {
    const int j = j0 + 2 * s;
    const v2f qx = *(const v2f*)&lrx[j];
    const v2f qy = *(const v2f*)&lry[j];
    const v2f qz = *(const v2f*)&lrz[j];
    const v2f dx = vX - qx;
    const v2f dy = vY - qy;
    const v2f dz = vZ - qz;
    const v2f d = (dx * dx + dy * dy) + dz * dz;
    const double p0 = mk_key(d[0], (u32)j);
    const double p1 = mk_key(d[1], (u32)(j + 1));
    best = fmin(best, fmin(p0, p1));
  }
  // pair combine across the two halves (lanes differ only in bit 0)
  const u64 bu = (u64)__double_as_longlong(best);
  const u64 ou = ((u64)(u32)__shfl_xor((int)(bu >> 32), 1, 64) << 32) |
                 (u64)(u32)__shfl_xor((int)(u32)bu, 1, 64);
  best = fmin(best, __longlong_as_double((long long)ou));
  if (half == 0) snn[r] = gidx[b * MPTS + (int)key_lo(best)];
  __syncthreads();

  // ---- assembly phase: 2 threads per row ----
  const int g = snn[r];
  float* o = out + (size_t)i * 134;
  if (half == 0) {
    // o[0..63] = x[i], o[64..66] = pos[i], zeros output
    const float4* xr = (const float4*)(x + (size_t)i * DIM);
#pragma unroll
    for (int q = 0; q < 16; ++q) {
      const float4 v = xr[q];
      *(v2f*)(o + 4 * q)     = v2f{v.x, v.y};   // 536B row stride: 8B aligned
      *(v2f*)(o + 4 * q + 2) = v2f{v.z, v.w};
    }
    o[64] = X; o[65] = Y; o[66] = Z;
    float* o2 = out + (size_t)BATCH * NPTS * 134 + (size_t)i * 3;
    o2[0] = 0.0f; o2[1] = 0.0f; o2[2] = 0.0f;
  } else {
    // o[67..130] = x[g], o[131..133] = pos[g], batch output
    const float4* xg = (const float4*)(x + (size_t)g * DIM);
    float e[64];
#pragma unroll
    for (int q = 0; q < 16; ++q) {
      const float4 v = xg[q];
      e[4 * q + 0] = v.x; e[4 * q + 1] = v.y;
      e[4 * q + 2] = v.z; e[4 * q + 3] = v.w;
    }
    o[67] = e[0];
#pragma unroll
    for (int m = 0; m < 31; ++m)
      *(v2f*)(o + 68 + 2 * m) = v2f{e[2 * m + 1], e[2 * m + 2]};  // even offs: 8B aligned
    o[130] = e[63];
    o[131] = pos[3 * g + 0];
    o[132] = pos[3 * g + 1];
    o[133] = pos[3 * g + 2];
    float* o3 = out + (size_t)BATCH * NPTS * 134 + (size_t)BATCH * NPTS * 3;
    o3[i] = (float)batch[i];
  }
}

// ---------------------------------------------------------------------------
extern "C" void kernel_launch(void* const* d_in, const int* in_sizes, int n_in,
                              void* d_out, int out_size, void* d_ws, size_t ws_size,
                              hipStream_t stream) {
  const float* x = (const float*)d_in[0];
  const float* pos = (const float*)d_in[1];
  const int* batch = (const int*)d_in[2];

  int* gidx = (int*)d_ws;  // [B*M] global indices of sampled points

  float* out = (float*)d_out;

  fps_kernel<<<BATCH, 256, 0, stream>>>(pos, gidx);
  nn_assemble_kernel<<<BATCH * 32, 256, 0, stream>>>(x, pos, batch, gidx, out);
}

// Round 5
// 568.829 us; speedup vs baseline: 1.1901x; 1.1901x over previous
//
#include <hip/hip_runtime.h>
#include <cstdint>

#define BATCH 8
#define NPTS  4096
#define MPTS  1024
#define DIM   64

typedef float v2f __attribute__((ext_vector_type(2)));
typedef unsigned long long u64;
typedef unsigned int u32;

// Pack (f32 distance bits, aux) into a double whose VALUE ordering equals the
// u64 bit-pattern ordering: hi word = f32 bits of a non-negative float
// (<= FLT_MAX bits 0x7F7FFFFF -> f64 exponent <= 2039, sign 0 -> positive
// finite double). So v_max_f64 / v_min_f64 (1 inst each) give exact u64
// max/min — replacing the 3-inst v_cmp_u64+2*cndmask sequence.
__device__ __forceinline__ double mk_key(float m, u32 aux) {
  const u64 k = ((u64)__float_as_uint(m) << 32) | (u64)aux;
  return __longlong_as_double((long long)k);
}
__device__ __forceinline__ u32 key_lo(double d) {
  return (u32)(u64)__double_as_longlong(d);
}

// One DPP step of a 64-lane f64-key max reduction. bound_ctrl=true -> invalid
// source lanes read 0.0, the identity for max of positive keys.
#define WAVE_MAX_F64_STEP(x, ctrl)                                                    \
  {                                                                                   \
    const u64 xu_ = (u64)__double_as_longlong(x);                                     \
    const int lo_ = __builtin_amdgcn_update_dpp(0, (int)(u32)xu_, (ctrl), 0xf, 0xf, true);  \
    const int hi_ = __builtin_amdgcn_update_dpp(0, (int)(u32)(xu_ >> 32), (ctrl), 0xf, 0xf, true); \
    const double y_ = __longlong_as_double((long long)(((u64)(u32)hi_ << 32) | (u64)(u32)lo_)); \
    (x) = fmax((x), y_);                                                              \
  }

// -------------------- Kernel 1: farthest point sampling --------------------
// EXACT R1 structure (best measured: 473 µs). One block per cloud, 256
// threads (4 waves, 1/SIMD), 16 points/thread as 8 float2 groups.
// Argmax key: (dist_bits<<32)|~idx -> max = largest dist, tie -> smallest idx
// (matches np.argmax). All 64-bit maxes via single v_max_f64 (see mk_key).
// 6-step DPP wave reduce, lane 63 writes wave slot, 1 barrier (double-buffered
// slots), 4-slot combine, winner coords via broadcast ds_read_b128.
// Zero VMEM in the steady-state loop: winner history kept in registers
// (thread t owns iterations t, t+256, t+512, t+768), written in the epilogue.
// Lessons locked in: R2 (more waves/SIMD duplicate reduce issue: -19%),
// R3 (f32+descent reduce: -9%), R4 (speculative scattered gather + readlane
// publish: -25%). The f64-key DPP reduce + two conserved LDS hops is the
// best-known form.
__global__ __launch_bounds__(256) void fps_kernel(const float* __restrict__ pos,
                                                  int* __restrict__ gidx) {
#pragma clang fp contract(off)
  const int b = blockIdx.x;
  const int t = threadIdx.x;
  const float* p = pos + (size_t)b * NPTS * 3;

  __shared__ float4 sp[NPTS];
  __shared__ double red[2][4];

  v2f px[8], py[8], pz[8], mind[8];
#pragma unroll
  for (int k = 0; k < 16; ++k) {
    const int i = t + k * 256;
    const float a = p[3 * i + 0];
    const float c = p[3 * i + 1];
    const float d = p[3 * i + 2];
    sp[i] = make_float4(a, c, d, 0.0f);
    px[k >> 1][k & 1] = a;
    py[k >> 1][k & 1] = c;
    pz[k >> 1][k & 1] = d;
    mind[k >> 1][k & 1] = 3.402823466e+38f;  // finfo(float32).max
  }
  __syncthreads();

  float4 w = sp[0];
  float lx = w.x, ly = w.y, lz = w.z;

  int h0 = 0, h1 = 0, h2 = 0, h3 = 0;
  const int it1 = t + 256, it2 = t + 512, it3 = t + 768;

  for (int it = 1; it < MPTS; ++it) {
    const v2f vlx = {lx, lx}, vly = {ly, ly}, vlz = {lz, lz};
    double pg[8];
#pragma unroll
    for (int g = 0; g < 8; ++g) {
      // strict fp32, no contraction: ((dx*dx + dy*dy) + dz*dz), per element
      const v2f dx = px[g] - vlx;
      const v2f dy = py[g] - vly;
      const v2f dz = pz[g] - vlz;
      const v2f d = (dx * dx + dy * dy) + dz * dz;
      const v2f m = __builtin_elementwise_min(mind[g], d);
      mind[g] = m;
      const double p0 = mk_key(m[0], ~(u32)(t + (2 * g) * 256));      // hoisted consts
      const double p1 = mk_key(m[1], ~(u32)(t + (2 * g + 1) * 256));  // tie -> larger ~idx
      pg[g] = fmax(p0, p1);
    }
    // thread-local tree (all single v_max_f64)
    const double b0 = fmax(pg[0], pg[1]);
    const double b1 = fmax(pg[2], pg[3]);
    const double b2 = fmax(pg[4], pg[5]);
    const double b3 = fmax(pg[6], pg[7]);
    double best = fmax(fmax(b0, b1), fmax(b2, b3));

    // 64-lane wave max via DPP: rows (16) then cross-row bcasts; lane 63 final.
    WAVE_MAX_F64_STEP(best, 0x111);  // row_shr:1
    WAVE_MAX_F64_STEP(best, 0x112);  // row_shr:2
    WAVE_MAX_F64_STEP(best, 0x114);  // row_shr:4
    WAVE_MAX_F64_STEP(best, 0x118);  // row_shr:8
    WAVE_MAX_F64_STEP(best, 0x142);  // row_bcast:15
    WAVE_MAX_F64_STEP(best, 0x143);  // row_bcast:31

    const int buf = it & 1;  // double-buffered slots: 1 barrier/iter
    if ((t & 63) == 63) red[buf][t >> 6] = best;
    __syncthreads();

    const double c = fmax(fmax(red[buf][0], red[buf][1]),
                          fmax(red[buf][2], red[buf][3]));
    const u32 widx = ~key_lo(c);  // low word = ~idx

    w = sp[widx];  // broadcast read (same address all lanes)
    lx = w.x; ly = w.y; lz = w.z;

    // off-critical-path register history update (4x cmp+cndmask, no VMEM)
    h0 = (it == t)   ? (int)widx : h0;
    h1 = (it == it1) ? (int)widx : h1;
    h2 = (it == it2) ? (int)widx : h2;
    h3 = (it == it3) ? (int)widx : h3;
  }

  // Epilogue: 4 coalesced stores per thread write all M winner indices.
  const int base = b * MPTS;
  const int goff = b * NPTS;
  gidx[base + t]       = goff + h0;
  gidx[base + 256 + t] = goff + h1;
  gidx[base + 512 + t] = goff + h2;
  gidx[base + 768 + t] = goff + h3;
}

// ---------------- Kernel 2: fused k=1 NN + output assembly -----------------
// B*32 blocks x 256 threads.
// Phase 1 (nn): 128 hr points/block, 2 threads per point splitting the
// M=1024 lr points in half; packed fp32; u64-key argmin (tie -> smallest j,
// matches np.argmin) via v_min_f64; pair combine via shfl_xor(1).
// nng stays in LDS (snn) — no global round-trip, one launch saved.
// Phase 2 (assembly) — R5 change: wave-coalesced. R4's version wrote 67
// floats per thread sequentially (stride-536B between threads, fully
// uncoalesced). Now each of the 4 waves assembles 32 rows with lane-parallel
// accesses: o[lane] = x[row*64+lane] etc. — one 256B transaction per
// wave-instruction, matching the R1 standalone assemble pattern.
__global__ __launch_bounds__(256) void nn_assemble_kernel(
    const float* __restrict__ x, const float* __restrict__ pos,
    const int* __restrict__ batch, const int* __restrict__ gidx,
    float* __restrict__ out) {
#pragma clang fp contract(off)
  const int b = blockIdx.x >> 5;
  const int chunk = blockIdx.x & 31;
  const int t = threadIdx.x;

  __shared__ float lrx[MPTS], lry[MPTS], lrz[MPTS];
  __shared__ int snn[128];

  for (int j = t; j < MPTS; j += 256) {
    const int g = gidx[b * MPTS + j];
    lrx[j] = pos[3 * g + 0];
    lry[j] = pos[3 * g + 1];
    lrz[j] = pos[3 * g + 2];
  }
  __syncthreads();

  const int r = t >> 1;      // local row 0..127
  const int half = t & 1;
  const int i = b * NPTS + chunk * 128 + r;  // global hr point index
  const float X = pos[3 * i + 0];
  const float Y = pos[3 * i + 1];
  const float Z = pos[3 * i + 2];
  const v2f vX = {X, X}, vY = {Y, Y}, vZ = {Z, Z};

  double best = __longlong_as_double(0x7FEFFFFFFFFFFFFFll);  // +DBL_MAX > all keys
  const int j0 = half * 512;
#pragma unroll 4
  for (int s = 0; s < 256; ++s) {
    const int j = j0 + 2 * s;
    const v2f qx = *(const v2f*)&lrx[j];
    const v2f qy = *(const v2f*)&lry[j];
    const v2f qz = *(const v2f*)&lrz[j];
    const v2f dx = vX - qx;
    const v2f dy = vY - qy;
    const v2f dz = vZ - qz;
    const v2f d = (dx * dx + dy * dy) + dz * dz;
    const double p0 = mk_key(d[0], (u32)j);
    const double p1 = mk_key(d[1], (u32)(j + 1));
    best = fmin(best, fmin(p0, p1));
  }
  // pair combine across the two halves (lanes differ only in bit 0)
  const u64 bu = (u64)__double_as_longlong(best);
  const u64 ou = ((u64)(u32)__shfl_xor((int)(bu >> 32), 1, 64) << 32) |
                 (u64)(u32)__shfl_xor((int)(u32)bu, 1, 64);
  best = fmin(best, __longlong_as_double((long long)ou));
  if (half == 0) snn[r] = gidx[b * MPTS + (int)key_lo(best)];
  __syncthreads();

  // ---- assembly phase: wave-coalesced, 32 rows per wave ----
  const int wid = t >> 6;
  const int lane = t & 63;
  const int rowbase = b * NPTS + chunk * 128;
#pragma unroll 4
  for (int n = 0; n < 32; ++n) {
    const int rr = wid * 32 + n;
    const int ii = rowbase + rr;
    const int g = snn[rr];
    float* o = out + (size_t)ii * 134;
    o[lane] = x[(size_t)ii * DIM + lane];        // coalesced 64-float row
    o[67 + lane] = x[(size_t)g * DIM + lane];    // coalesced row gather
    if (lane < 3) {
      o[64 + lane] = pos[3 * ii + lane];
      o[131 + lane] = pos[3 * g + lane];
    }
  }
  // zeros output [B*N,3] and batch output [B*N], block-strided coalesced
  float* o2 = out + (size_t)BATCH * NPTS * 134 + (size_t)rowbase * 3;
  for (int q = t; q < 384; q += 256) o2[q] = 0.0f;
  float* o3 = out + (size_t)BATCH * NPTS * 134 + (size_t)BATCH * NPTS * 3;
  if (t < 128) o3[rowbase + t] = (float)b;  // batch[i] == b by construction
}

// ---------------------------------------------------------------------------
extern "C" void kernel_launch(void* const* d_in, const int* in_sizes, int n_in,
                              void* d_out, int out_size, void* d_ws, size_t ws_size,
                              hipStream_t stream) {
  const float* x = (const float*)d_in[0];
  const float* pos = (const float*)d_in[1];
  const int* batch = (const int*)d_in[2];

  int* gidx = (int*)d_ws;  // [B*M] global indices of sampled points

  float* out = (float*)d_out;

  fps_kernel<<<BATCH, 256, 0, stream>>>(pos, gidx);
  nn_assemble_kernel<<<BATCH * 32, 256, 0, stream>>>(x, pos, batch, gidx, out);
}

// Round 7
// 563.694 us; speedup vs baseline: 1.2010x; 1.0091x over previous
//
#include <hip/hip_runtime.h>
#include <cstdint>

#define BATCH 8
#define NPTS  4096
#define MPTS  1024
#define DIM   64
#define SA_BLOCKS 128  // static-assembly blocks riding along with fps

typedef float v2f __attribute__((ext_vector_type(2)));
typedef unsigned long long u64;
typedef unsigned int u32;

// Pack (f32 distance bits, aux) into a double whose VALUE ordering equals the
// u64 bit-pattern ordering: hi word = f32 bits of a non-negative float
// (<= FLT_MAX bits 0x7F7FFFFF -> f64 exponent <= 2039, sign 0 -> positive
// finite double). So v_max_f64 / v_min_f64 (1 inst each) give exact u64
// max/min — replacing the 3-inst v_cmp_u64+2*cndmask sequence.
__device__ __forceinline__ double mk_key(float m, u32 aux) {
  const u64 k = ((u64)__float_as_uint(m) << 32) | (u64)aux;
  return __longlong_as_double((long long)k);
}
__device__ __forceinline__ u32 key_lo(double d) {
  return (u32)(u64)__double_as_longlong(d);
}

// One DPP step of a 64-lane f64-key max reduction. bound_ctrl=true -> invalid
// source lanes read 0.0, the identity for max of positive keys.
#define WAVE_MAX_F64_STEP(x, ctrl)                                                    \
  {                                                                                   \
    const u64 xu_ = (u64)__double_as_longlong(x);                                     \
    const int lo_ = __builtin_amdgcn_update_dpp(0, (int)(u32)xu_, (ctrl), 0xf, 0xf, true);  \
    const int hi_ = __builtin_amdgcn_update_dpp(0, (int)(u32)(xu_ >> 32), (ctrl), 0xf, 0xf, true); \
    const double y_ = __longlong_as_double((long long)(((u64)(u32)hi_ << 32) | (u64)(u32)lo_)); \
    (x) = fmax((x), y_);                                                              \
  }

// ------------- Kernel 1: FPS + overlapped static output assembly -----------
// Grid-union fuse: blocks 0..7 run the (unchanged, best-known R1) FPS loop on
// 8 CUs; blocks 8..135 concurrently write every output column that does NOT
// depend on FPS/NN: out[:, 0..66] = [x | pos], the zeros output, and the
// batch output (~22 MB of traffic executed in the 474 µs shadow of the FPS
// serial loop — previously serialized after it). Streams can't overlap
// launches, a shared grid can.
// FPS core (R1, 473 µs): 256 threads (4 waves, 1/SIMD), 16 pts/thread as 8
// float2 groups; u64-key argmax (tie -> smallest idx, matches np.argmax) via
// v_max_f64; 6-step DPP wave reduce; 1 barrier/iter (double-buffered slots);
// winner coords via broadcast ds_read_b128; zero VMEM in the loop (winner
// history in registers, thread t owns iterations t+256k). Locked lessons:
// R2 more waves -19%, R3 f32-descent reduce -9%, R4 speculative gather -25%.
__global__ __launch_bounds__(256) void fps_static_kernel(
    const float* __restrict__ pos, const float* __restrict__ x,
    int* __restrict__ gidx, float* __restrict__ out) {
#pragma clang fp contract(off)
  const int t = threadIdx.x;

  if (blockIdx.x >= BATCH) {
    // ---- static assembly: 256 rows per block, wave-coalesced ----
    const int sb = blockIdx.x - BATCH;
    const int wid = t >> 6;
    const int lane = t & 63;
    const int rowbase = sb * 256;
#pragma unroll 4
    for (int n = 0; n < 64; ++n) {
      const int row = rowbase + wid * 64 + n;
      float* o = out + (size_t)row * 134;
      o[lane] = x[(size_t)row * DIM + lane];     // coalesced 64-float row
      if (lane < 3) o[64 + lane] = pos[3 * row + lane];
    }
    float* o2 = out + (size_t)BATCH * NPTS * 134 + (size_t)rowbase * 3;
    for (int q = t; q < 768; q += 256) o2[q] = 0.0f;  // zeros output [B*N,3]
    float* o3 = out + (size_t)BATCH * NPTS * 134 + (size_t)BATCH * NPTS * 3;
    o3[rowbase + t] = (float)((rowbase + t) >> 12);   // batch id = row/NPTS
    return;
  }

  const int b = blockIdx.x;
  const float* p = pos + (size_t)b * NPTS * 3;

  __shared__ float4 sp[NPTS];
  __shared__ double red[2][4];

  v2f px[8], py[8], pz[8], mind[8];
#pragma unroll
  for (int k = 0; k < 16; ++k) {
    const int i = t + k * 256;
    const float a = p[3 * i + 0];
    const float c = p[3 * i + 1];
    const float d = p[3 * i + 2];
    sp[i] = make_float4(a, c, d, 0.0f);
    px[k >> 1][k & 1] = a;
    py[k >> 1][k & 1] = c;
    pz[k >> 1][k & 1] = d;
    mind[k >> 1][k & 1] = 3.402823466e+38f;  // finfo(float32).max
  }
  __syncthreads();

  float4 w = sp[0];
  float lx = w.x, ly = w.y, lz = w.z;

  int h0 = 0, h1 = 0, h2 = 0, h3 = 0;
  const int it1 = t + 256, it2 = t + 512, it3 = t + 768;

  for (int it = 1; it < MPTS; ++it) {
    const v2f vlx = {lx, lx}, vly = {ly, ly}, vlz = {lz, lz};
    double pg[8];
#pragma unroll
    for (int g = 0; g < 8; ++g) {
      // strict fp32, no contraction: ((dx*dx + dy*dy) + dz*dz), per element
      const v2f dx = px[g] - vlx;
      const v2f dy = py[g] - vly;
      const v2f dz = pz[g] - vlz;
      const v2f d = (dx * dx + dy * dy) + dz * dz;
      const v2f m = __builtin_elementwise_min(mind[g], d);
      mind[g] = m;
      const double p0 = mk_key(m[0], ~(u32)(t + (2 * g) * 256));      // hoisted consts
      const double p1 = mk_key(m[1], ~(u32)(t + (2 * g + 1) * 256));  // tie -> larger ~idx
      pg[g] = fmax(p0, p1);
    }
    // thread-local tree (all single v_max_f64)
    const double b0 = fmax(pg[0], pg[1]);
    const double b1 = fmax(pg[2], pg[3]);
    const double b2 = fmax(pg[4], pg[5]);
    const double b3 = fmax(pg[6], pg[7]);
    double best = fmax(fmax(b0, b1), fmax(b2, b3));

    // 64-lane wave max via DPP: rows (16) then cross-row bcasts; lane 63 final.
    WAVE_MAX_F64_STEP(best, 0x111);  // row_shr:1
    WAVE_MAX_F64_STEP(best, 0x112);  // row_shr:2
    WAVE_MAX_F64_STEP(best, 0x114);  // row_shr:4
    WAVE_MAX_F64_STEP(best, 0x118);  // row_shr:8
    WAVE_MAX_F64_STEP(best, 0x142);  // row_bcast:15
    WAVE_MAX_F64_STEP(best, 0x143);  // row_bcast:31

    const int buf = it & 1;  // double-buffered slots: 1 barrier/iter
    if ((t & 63) == 63) red[buf][t >> 6] = best;
    __syncthreads();

    const double c = fmax(fmax(red[buf][0], red[buf][1]),
                          fmax(red[buf][2], red[buf][3]));
    const u32 widx = ~key_lo(c);  // low word = ~idx

    w = sp[widx];  // broadcast read (same address all lanes)
    lx = w.x; ly = w.y; lz = w.z;

    // off-critical-path register history update (4x cmp+cndmask, no VMEM)
    h0 = (it == t)   ? (int)widx : h0;
    h1 = (it == it1) ? (int)widx : h1;
    h2 = (it == it2) ? (int)widx : h2;
    h3 = (it == it3) ? (int)widx : h3;
  }

  // Epilogue: 4 coalesced stores per thread write all M winner indices.
  const int base = b * MPTS;
  const int goff = b * NPTS;
  gidx[base + t]       = goff + h0;
  gidx[base + 256 + t] = goff + h1;
  gidx[base + 512 + t] = goff + h2;
  gidx[base + 768 + t] = goff + h3;
}

// ------------- Kernel 2: k=1 NN + gather-dependent assembly ----------------
// B*32 blocks x 256 threads.
// Phase 1 (nn): 128 hr points/block, 2 threads per point splitting the
// M=1024 lr points in half; packed fp32; u64-key argmin (tie -> smallest j,
// matches np.argmin) via v_min_f64; pair combine via shfl_xor(1). nng stays
// in LDS (snn).
// Phase 2: only the FPS/NN-dependent columns remain (out[:,67..133] =
// [x[g] | pos[g]]) — the static columns are written by fps_static_kernel's
// rider blocks. Wave-coalesced: 32 rows per wave, lane-parallel.
__global__ __launch_bounds__(256) void nn_dyn_kernel(
    const float* __restrict__ x, const float* __restrict__ pos,
    const int* __restrict__ gidx, float* __restrict__ out) {
#pragma clang fp contract(off)
  const int b = blockIdx.x >> 5;
  const int chunk = blockIdx.x & 31;
  const int t = threadIdx.x;

  __shared__ float lrx[MPTS], lry[MPTS], lrz[MPTS];
  __shared__ int snn[128];

  for (int j = t; j < MPTS; j += 256) {
    const int g = gidx[b * MPTS + j];
    lrx[j] = pos[3 * g + 0];
    lry[j] = pos[3 * g + 1];
    lrz[j] = pos[3 * g + 2];
  }
  __syncthreads();

  const int r = t >> 1;      // local row 0..127
  const int half = t & 1;
  const int i = b * NPTS + chunk * 128 + r;  // global hr point index
  const float X = pos[3 * i + 0];
  const float Y = pos[3 * i + 1];
  const float Z = pos[3 * i + 2];
  const v2f vX = {X, X}, vY = {Y, Y}, vZ = {Z, Z};

  double best = __longlong_as_double(0x7FEFFFFFFFFFFFFFll);  // +DBL_MAX > all keys
  const int j0 = half * 512;
#pragma unroll 4
  for (int s = 0; s < 256; ++s) {
    const int j = j0 + 2 * s;
    const v2f qx = *(const v2f*)&lrx[j];
    const v2f qy = *(const v2f*)&lry[j];
    const v2f qz = *(const v2f*)&lrz[j];
    const v2f dx = vX - qx;
    const v2f dy = vY - qy;
    const v2f dz = vZ - qz;
    const v2f d = (dx * dx + dy * dy) + dz * dz;
    const double p0 = mk_key(d[0], (u32)j);
    const double p1 = mk_key(d[1], (u32)(j + 1));
    best = fmin(best, fmin(p0, p1));
  }
  // pair combine across the two halves (lanes differ only in bit 0)
  const u64 bu = (u64)__double_as_longlong(best);
  const u64 ou = ((u64)(u32)__shfl_xor((int)(bu >> 32), 1, 64) << 32) |
                 (u64)(u32)__shfl_xor((int)(u32)bu, 1, 64);
  best = fmin(best, __longlong_as_double((long long)ou));
  if (half == 0) snn[r] = gidx[b * MPTS + (int)key_lo(best)];
  __syncthreads();

  // ---- dependent assembly: wave-coalesced, 32 rows per wave ----
  const int wid = t >> 6;
  const int lane = t & 63;
  const int rowbase = b * NPTS + chunk * 128;
#pragma unroll 4
  for (int n = 0; n < 32; ++n) {
    const int rr = wid * 32 + n;
    const int ii = rowbase + rr;
    const int g = snn[rr];
    float* o = out + (size_t)ii * 134;
    o[67 + lane] = x[(size_t)g * DIM + lane];    // coalesced row gather
    if (lane < 3) o[131 + lane] = pos[3 * g + lane];
  }
}

// ---------------------------------------------------------------------------
extern "C" void kernel_launch(void* const* d_in, const int* in_sizes, int n_in,
                              void* d_out, int out_size, void* d_ws, size_t ws_size,
                              hipStream_t stream) {
  const float* x = (const float*)d_in[0];
  const float* pos = (const float*)d_in[1];

  int* gidx = (int*)d_ws;  // [B*M] global indices of sampled points

  float* out = (float*)d_out;

  fps_static_kernel<<<BATCH + SA_BLOCKS, 256, 0, stream>>>(pos, x, gidx, out);
  nn_dyn_kernel<<<BATCH * 32, 256, 0, stream>>>(x, pos, gidx, out);
}